// Round 5
// baseline (17039.630 us; speedup 1.0000x reference)
//
#include <hip/hip_runtime.h>
#include <stdint.h>

typedef int i32x4  __attribute__((ext_vector_type(4)));
typedef int i32x16 __attribute__((ext_vector_type(16)));

constexpr int Bsz  = 4096;
constexpr int Tst  = 20;
constexpr int Fin  = 2000;
constexpr int H1   = 512;
constexpr int H2   = 128;
constexpr int NOUT = 10;
constexpr int FW   = 64;     // words per layer-1 spike row (2048 bits)

// ---------------- Threefry-2x32-20, key = jax.random.key(1) = [0,1] ----------------
__device__ __forceinline__ void tf2x32(uint32_t c0, uint32_t c1, uint32_t& o0, uint32_t& o1) {
  const uint32_t k0 = 0u, k1 = 1u, k2 = 0x1BD11BDBu;
  uint32_t x0 = c0 + k0;
  uint32_t x1 = c1 + k1;
#define ROTL(x,d) (((x)<<(d))|((x)>>(32-(d))))
#define RND(r) { x0 += x1; x1 = ROTL(x1,(r)) ^ x0; }
  RND(13) RND(15) RND(26) RND(6)   x0 += k1; x1 += k2 + 1u;
  RND(17) RND(29) RND(16) RND(24)  x0 += k2; x1 += k0 + 2u;
  RND(13) RND(15) RND(26) RND(6)   x0 += k0; x1 += k1 + 3u;
  RND(17) RND(29) RND(16) RND(24)  x0 += k1; x1 += k2 + 4u;
  RND(13) RND(15) RND(26) RND(6)   x0 += k2; x1 += k0 + 5u;
#undef RND
#undef ROTL
  o0 = x0; o1 = x1;
}

// Partitionable threefry: counter = (0, flat_idx), bits = o0^o1. (verified round 2)
__global__ void spikegen(const float* __restrict__ x, uint32_t* __restrict__ sbits) {
  int gid = blockIdx.x * blockDim.x + threadIdx.x;
  if (gid >= Bsz * Tst * FW) return;
  int w = gid & 63;
  int row = gid >> 6;                 // b*T + t
  int b = row / Tst;
  uint32_t bits = 0;
  int fbase = w * 32;
  const float* xr = x + (size_t)b * Fin;
  uint32_t ibase = (uint32_t)row * (uint32_t)Fin;
  for (int j = 0; j < 32; ++j) {
    int f = fbase + j;
    if (f >= Fin) break;
    uint32_t o0, o1;
    tf2x32(0u, ibase + (uint32_t)f, o0, o1);
    uint32_t m = o0 ^ o1;
    float u = __uint_as_float((m >> 9) | 0x3f800000u) - 1.0f;
    if (u < xr[f]) bits |= (1u << j);
  }
  sbits[(size_t)row * FW + w] = bits;
}

// Decompose W into 5 balanced base-256 int8 digits on grid 2^-40, written in
// MFMA-fragment-tiled order: Btl[s][nt][kst][ (khalf*32+col)*16 + j ].
__global__ void wslice_i8(const float* __restrict__ W, int O, int K, int KPAD,
                          int8_t* __restrict__ Btl) {
  int idx = blockIdx.x * 256 + threadIdx.x;
  if (idx >= O * KPAD) return;
  int o = idx / KPAD, f = idx % KPAD;
  long long wi = 0;
  if (f < K) wi = llround((double)W[(size_t)o * K + f] * 1099511627776.0);  // 2^40
  int nt = o >> 5, c = o & 31, kst = f >> 5, kh = (f >> 4) & 1, j = f & 15;
  int NT = O >> 5, KST = KPAD >> 5;
  size_t base = (((size_t)nt * KST + kst) << 10) + (size_t)(kh * 32 + c) * 16 + j;
  size_t sstride = ((size_t)NT * KST) << 10;
  long long rem = wi;
#pragma unroll
  for (int s = 0; s < 5; ++s) {
    int d;
    if (s < 4) { d = (int)(int8_t)(rem & 0xff); rem = (rem - d) >> 8; }
    else d = (int)rem;                       // |d| small (|w| <= ~0.12)
    Btl[base + (size_t)s * sstride] = (int8_t)d;
  }
}

// ---------------- i8 MFMA slice GEMM ----------------
typedef const __attribute__((address_space(1))) uint32_t* gas_ptr;
typedef __attribute__((address_space(3))) uint32_t* las_ptr;
__device__ __forceinline__ void gld16(const void* g, void* l) {
  __builtin_amdgcn_global_load_lds((gas_ptr)g, (las_ptr)l, 16, 0, 0);
}

// C[r][col] = (sum_f A_bits[r][f]*W[col][f]) + bias[col], exact via 5 i8 digit slices.
// Block: 320 threads = 5 waves (wave = slice). Tile 64 rows x 64 cols.
template <int KPAD, int O>
__global__ __launch_bounds__(320) void gemm_i8(
    const uint32_t* __restrict__ Abits, int awords, int rowBase,
    const int8_t* __restrict__ Btl, const float* __restrict__ bias,
    double* __restrict__ Cout) {
  constexpr int KST = KPAD / 32;
  constexpr int NT = O / 32;
  __shared__ __align__(16) char smem[40960];
  const int tid = threadIdx.x;
  const int lane = tid & 63;
  const int s = tid >> 6;                 // wave id = slice id
  const int row0 = blockIdx.x * 64;
  const int col0 = blockIdx.y * 64;
  const int nt0 = blockIdx.y * 2;
  const int lrow = lane & 31, lkh = lane >> 5;

  i32x16 acc[2][2] = {};

  // A bit source (waves 0,1 stage m-half = s): 16 bits per lane per K-step.
  // Row stride = awords*4 bytes; K-step stride = 4 bytes (32 bits).
  const uint8_t* arowp = (const uint8_t*)Abits +
      (size_t)(rowBase + row0 + s * 32 + lrow) * (size_t)(awords * 4) + (size_t)(lkh * 2);
  // B tiled source for this wave's slice (1KB fragment blocks)
  const int8_t* bsrc0 = Btl + ((((size_t)s * NT + nt0) * KST) << 10) + (size_t)lane * 16;
  const int8_t* bsrc1 = Btl + ((((size_t)s * NT + nt0 + 1) * KST) << 10) + (size_t)lane * 16;

  char* sA = smem;             // [2 buf][2 m][1024]
  char* sBs = smem + 4096 + s * 4096;  // this slice: [2 buf][2 nf][1024]

#define STAGE(buf, kst) do {                                                       \
    if (s < 2) {                                                                   \
      uint32_t bits16 = *(const unsigned short*)(arowp + (size_t)(kst) * 4);       \
      uint32_t n0 = bits16 & 0xF, n1 = (bits16 >> 4) & 0xF,                        \
               n2 = (bits16 >> 8) & 0xF, n3 = (bits16 >> 12) & 0xF;                \
      uint4 dv = make_uint4(                                                       \
        (n0 & 1) | ((n0 & 2) << 7) | ((n0 & 4) << 14) | ((n0 & 8) << 21),          \
        (n1 & 1) | ((n1 & 2) << 7) | ((n1 & 4) << 14) | ((n1 & 8) << 21),          \
        (n2 & 1) | ((n2 & 2) << 7) | ((n2 & 4) << 14) | ((n2 & 8) << 21),          \
        (n3 & 1) | ((n3 & 2) << 7) | ((n3 & 4) << 14) | ((n3 & 8) << 21));         \
      *(uint4*)(sA + (buf) * 2048 + s * 1024 + lane * 16) = dv;                    \
    }                                                                              \
    gld16(bsrc0 + ((size_t)(kst) << 10), sBs + (buf) * 2048 + lane * 16);          \
    gld16(bsrc1 + ((size_t)(kst) << 10), sBs + (buf) * 2048 + 1024 + lane * 16);   \
  } while (0)

  STAGE(0, 0);
  __syncthreads();

#pragma unroll 1
  for (int kst = 0; kst < KST; ++kst) {
    const int buf = kst & 1;
    if (kst + 1 < KST) STAGE(buf ^ 1, kst + 1);
    uint4 av0 = *(const uint4*)(sA + buf * 2048 + lane * 16);
    uint4 av1 = *(const uint4*)(sA + buf * 2048 + 1024 + lane * 16);
    uint4 bv0 = *(const uint4*)(sBs + buf * 2048 + lane * 16);
    uint4 bv1 = *(const uint4*)(sBs + buf * 2048 + 1024 + lane * 16);
    i32x4 a0 = __builtin_bit_cast(i32x4, av0), a1 = __builtin_bit_cast(i32x4, av1);
    i32x4 b0 = __builtin_bit_cast(i32x4, bv0), b1 = __builtin_bit_cast(i32x4, bv1);
    acc[0][0] = __builtin_amdgcn_mfma_i32_32x32x32_i8(a0, b0, acc[0][0], 0, 0, 0);
    acc[0][1] = __builtin_amdgcn_mfma_i32_32x32x32_i8(a0, b1, acc[0][1], 0, 0, 0);
    acc[1][0] = __builtin_amdgcn_mfma_i32_32x32x32_i8(a1, b0, acc[1][0], 0, 0, 0);
    acc[1][1] = __builtin_amdgcn_mfma_i32_32x32x32_i8(a1, b1, acc[1][1], 0, 0, 0);
    __syncthreads();
  }
#undef STAGE

  // Epilogue: exact i64 combine of the 5 slices via LDS, f64 output.
  int* red = (int*)smem;   // [5][64 rows][32 cols]
#pragma unroll 1
  for (int n = 0; n < 2; ++n) {
    __syncthreads();
#pragma unroll
    for (int m = 0; m < 2; ++m)
#pragma unroll
      for (int r = 0; r < 16; ++r) {
        int row = m * 32 + (r & 3) + ((r >> 2) << 3) + ((lane >> 5) << 2);
        red[(s * 64 + row) * 32 + (lane & 31)] = acc[m][n][r];
      }
    __syncthreads();
    for (int e = tid; e < 2048; e += 320) {
      int row = e >> 5, c = e & 31;
      long long v = 0;
#pragma unroll
      for (int s5 = 0; s5 < 5; ++s5)
        v += (long long)red[(s5 * 64 + row) * 32 + c] * (1LL << (8 * s5));
      int col = col0 + n * 32 + c;
      Cout[(size_t)(row0 + row) * O + col] = (double)v * 0x1p-40 + (double)bias[col];
    }
  }
}

// LIF layer 1: one block per batch row of chunk, 512 threads = H1 neurons.
__global__ __launch_bounds__(512) void lif1(const double* __restrict__ inp1,
                                            uint32_t* __restrict__ spk1, int bBase) {
  int b_local = blockIdx.x;
  int o = threadIdx.x;
  int b = bBase + b_local;
  double mem = 0.0;
  for (int t = 0; t < Tst; ++t) {
    double inp = inp1[((size_t)(b_local * Tst + t)) * H1 + o];
    mem = mem + (inp - mem) / 2.0;
    bool spk = (mem >= 1.0);
    unsigned long long m = __ballot(spk);
    if ((o & 63) == 0) {
      int wv = o >> 6;
      size_t base = ((size_t)(b * Tst + t)) * (H1 / 32);
      spk1[base + wv * 2]     = (uint32_t)(m & 0xffffffffu);
      spk1[base + wv * 2 + 1] = (uint32_t)(m >> 32);
    }
    if (spk) mem = 0.0;
  }
}

// LIF layer 2: one block per batch row of chunk; final membrane out.
__global__ __launch_bounds__(128) void lif2(const double* __restrict__ inp2,
                                            double* __restrict__ mem2, int bBase) {
  int b_local = blockIdx.x;
  int o = threadIdx.x;
  double mem = 0.0;
  for (int t = 0; t < Tst; ++t) {
    double inp = inp2[((size_t)(b_local * Tst + t)) * H2 + o];
    mem = mem + (inp - mem) / 2.0;
    if (mem >= 1.0) mem = 0.0;
  }
  mem2[(size_t)(bBase + b_local) * H2 + o] = mem;
}

// out = mem2 @ Wd^T + bd
__global__ void finalk(const double* __restrict__ mem2, const float* __restrict__ Wd,
                       const float* __restrict__ bd, float* __restrict__ out) {
  int gid = blockIdx.x * blockDim.x + threadIdx.x;
  if (gid >= Bsz * NOUT) return;
  int b = gid / NOUT, j = gid % NOUT;
  double s = (double)bd[j];
  const double* m = mem2 + (size_t)b * H2;
  const float* wr = Wd + (size_t)j * H2;
  for (int k = 0; k < H2; ++k) s = fma(m[k], (double)wr[k], s);
  out[gid] = (float)s;
}

extern "C" void kernel_launch(void* const* d_in, const int* in_sizes, int n_in,
                              void* d_out, int out_size, void* d_ws, size_t ws_size,
                              hipStream_t stream) {
  const float* x  = (const float*)d_in[0];
  const float* W1 = (const float*)d_in[1];
  const float* b1 = (const float*)d_in[2];
  const float* W2 = (const float*)d_in[3];
  const float* b2 = (const float*)d_in[4];
  const float* Wd = (const float*)d_in[5];
  const float* bd = (const float*)d_in[6];
  float* out = (float*)d_out;

  char* ws = (char*)d_ws;
  // Layout (bytes), total ~78 MB:
  double*   inp   = (double*)  (ws);                  // 41,943,040 (chunk inp, reused)
  double*   mem2  = (double*)  (ws + 41943040ull);    //  4,194,304
  uint32_t* sbits = (uint32_t*)(ws + 46137344ull);    // 20,971,520
  uint32_t* spk1  = (uint32_t*)(ws + 67108864ull);    //  5,242,880
  int8_t*   Btl1  = (int8_t*)  (ws + 72351744ull);    //  5,242,880 (5*16*64*1024)
  int8_t*   Btl2  = (int8_t*)  (ws + 77594624ull);    //    327,680 (5*4*16*1024)

  // 1) exact Poisson spike train (bit-packed)
  spikegen<<<dim3(Bsz * Tst * FW / 256), dim3(256), 0, stream>>>(x, sbits);

  // 2) weight digit decomposition (fragment-tiled)
  wslice_i8<<<dim3(512 * 2048 / 256), dim3(256), 0, stream>>>(W1, 512, 2000, 2048, Btl1);
  wslice_i8<<<dim3(128 * 512 / 256),  dim3(256), 0, stream>>>(W2, 128, 512, 512, Btl2);

  // 3) layer 1: 8 chunks of 10240 rows (512 batches)
  for (int c = 0; c < 8; ++c) {
    gemm_i8<2048, 512><<<dim3(160, 8), dim3(320), 0, stream>>>(
        sbits, FW, c * 10240, Btl1, b1, inp);
    lif1<<<dim3(512), dim3(H1), 0, stream>>>(inp, spk1, c * 512);
  }

  // 4) layer 2: 4 chunks of 20480 rows (1024 batches)
  for (int c = 0; c < 4; ++c) {
    gemm_i8<512, 128><<<dim3(320, 2), dim3(320), 0, stream>>>(
        spk1, H1 / 32, c * 20480, Btl2, b2, inp);
    lif2<<<dim3(1024), dim3(H2), 0, stream>>>(inp, mem2, c * 1024);
  }

  // 5) readout
  finalk<<<dim3((Bsz * NOUT + 255) / 256), dim3(256), 0, stream>>>(mem2, Wd, bd, out);
}

// Round 6
// 1447.185 us; speedup vs baseline: 11.7743x; 11.7743x over previous
//
#include <hip/hip_runtime.h>
#include <stdint.h>

typedef int i32x4  __attribute__((ext_vector_type(4)));
typedef int i32x16 __attribute__((ext_vector_type(16)));

constexpr int Bsz  = 4096;
constexpr int Tst  = 20;
constexpr int Fin  = 2000;
constexpr int H1   = 512;
constexpr int H2   = 128;
constexpr int NOUT = 10;
constexpr int FW   = 64;     // words per layer-1 spike row (2048 bits)

// ---------------- Threefry-2x32-20, key = jax.random.key(1) = [0,1] ----------------
__device__ __forceinline__ void tf2x32(uint32_t c0, uint32_t c1, uint32_t& o0, uint32_t& o1) {
  const uint32_t k0 = 0u, k1 = 1u, k2 = 0x1BD11BDBu;
  uint32_t x0 = c0 + k0;
  uint32_t x1 = c1 + k1;
#define ROTL(x,d) (((x)<<(d))|((x)>>(32-(d))))
#define RND(r) { x0 += x1; x1 = ROTL(x1,(r)) ^ x0; }
  RND(13) RND(15) RND(26) RND(6)   x0 += k1; x1 += k2 + 1u;
  RND(17) RND(29) RND(16) RND(24)  x0 += k2; x1 += k0 + 2u;
  RND(13) RND(15) RND(26) RND(6)   x0 += k0; x1 += k1 + 3u;
  RND(17) RND(29) RND(16) RND(24)  x0 += k1; x1 += k2 + 4u;
  RND(13) RND(15) RND(26) RND(6)   x0 += k2; x1 += k0 + 5u;
#undef RND
#undef ROTL
  o0 = x0; o1 = x1;
}

// Partitionable threefry: counter = (0, flat_idx), bits = o0^o1. (verified round 2)
__global__ void spikegen(const float* __restrict__ x, uint32_t* __restrict__ sbits) {
  int gid = blockIdx.x * blockDim.x + threadIdx.x;
  if (gid >= Bsz * Tst * FW) return;
  int w = gid & 63;
  int row = gid >> 6;                 // b*T + t
  int b = row / Tst;
  uint32_t bits = 0;
  int fbase = w * 32;
  const float* xr = x + (size_t)b * Fin;
  uint32_t ibase = (uint32_t)row * (uint32_t)Fin;
  for (int j = 0; j < 32; ++j) {
    int f = fbase + j;
    if (f >= Fin) break;
    uint32_t o0, o1;
    tf2x32(0u, ibase + (uint32_t)f, o0, o1);
    uint32_t m = o0 ^ o1;
    float u = __uint_as_float((m >> 9) | 0x3f800000u) - 1.0f;
    if (u < xr[f]) bits |= (1u << j);
  }
  sbits[(size_t)row * FW + w] = bits;
}

// Decompose W into 5 balanced base-256 int8 digits on grid 2^-40, written in
// MFMA-fragment-tiled order: Btl[s][nt][kst][ (khalf*32+col)*16 + j ].
__global__ void wslice_i8(const float* __restrict__ W, int O, int K, int KPAD,
                          int8_t* __restrict__ Btl) {
  int idx = blockIdx.x * 256 + threadIdx.x;
  if (idx >= O * KPAD) return;
  int o = idx / KPAD, f = idx % KPAD;
  long long wi = 0;
  if (f < K) wi = llround((double)W[(size_t)o * K + f] * 1099511627776.0);  // 2^40
  int nt = o >> 5, c = o & 31, kst = f >> 5, kh = (f >> 4) & 1, j = f & 15;
  int NT = O >> 5, KST = KPAD >> 5;
  size_t base = (((size_t)nt * KST + kst) << 10) + (size_t)(kh * 32 + c) * 16 + j;
  size_t sstride = ((size_t)NT * KST) << 10;
  long long rem = wi;
#pragma unroll
  for (int s = 0; s < 5; ++s) {
    int d;
    if (s < 4) { d = (int)(int8_t)(rem & 0xff); rem = (rem - d) >> 8; }
    else d = (int)rem;                       // |d| small (|w| <= ~0.12)
    Btl[base + (size_t)s * sstride] = (int8_t)d;
  }
}

// ---------------- i8 MFMA slice GEMM ----------------
typedef const __attribute__((address_space(1))) uint32_t* gas_ptr;
typedef __attribute__((address_space(3))) uint32_t* las_ptr;
__device__ __forceinline__ void gld16(const void* g, void* l) {
  __builtin_amdgcn_global_load_lds((gas_ptr)g, (las_ptr)l, 16, 0, 0);
}

// C[r][col] = (sum_f A_bits[r][f]*W[col][f]) + bias[col], exact via 5 i8 digit slices.
// Block: 320 threads = 5 waves (wave = slice). Tile 64 rows x 64 cols.
template <int KPAD, int O>
__global__ __launch_bounds__(320) void gemm_i8(
    const uint32_t* __restrict__ Abits, int awords, int rowBase,
    const int8_t* __restrict__ Btl, const float* __restrict__ bias,
    double* __restrict__ Cout) {
  constexpr int KST = KPAD / 32;
  constexpr int NT = O / 32;
  __shared__ __align__(16) char smem[40960];
  const int tid = threadIdx.x;
  const int lane = tid & 63;
  const int s = tid >> 6;                 // wave id = slice id
  const int row0 = blockIdx.x * 64;
  const int col0 = blockIdx.y * 64;
  const int nt0 = blockIdx.y * 2;
  const int lrow = lane & 31, lkh = lane >> 5;

  i32x16 acc[2][2] = {};

  // A bit source (waves 0,1 stage m-half = s): 16 bits per lane per K-step.
  // Row stride = awords*4 bytes; K-step stride = 4 bytes (32 bits).
  const uint8_t* arowp = (const uint8_t*)Abits +
      (size_t)(rowBase + row0 + s * 32 + lrow) * (size_t)(awords * 4) + (size_t)(lkh * 2);
  // B tiled source for this wave's slice (1KB fragment blocks)
  const int8_t* bsrc0 = Btl + ((((size_t)s * NT + nt0) * KST) << 10) + (size_t)lane * 16;
  const int8_t* bsrc1 = Btl + ((((size_t)s * NT + nt0 + 1) * KST) << 10) + (size_t)lane * 16;

  char* sA = smem;             // [2 buf][2 m][1024]
  char* sBs = smem + 4096 + s * 4096;  // this slice: [2 buf][2 nf][1024]

#define STAGE(buf, kst) do {                                                       \
    if (s < 2) {                                                                   \
      uint32_t bits16 = *(const unsigned short*)(arowp + (size_t)(kst) * 4);       \
      uint32_t n0 = bits16 & 0xF, n1 = (bits16 >> 4) & 0xF,                        \
               n2 = (bits16 >> 8) & 0xF, n3 = (bits16 >> 12) & 0xF;                \
      uint4 dv = make_uint4(                                                       \
        (n0 & 1) | ((n0 & 2) << 7) | ((n0 & 4) << 14) | ((n0 & 8) << 21),          \
        (n1 & 1) | ((n1 & 2) << 7) | ((n1 & 4) << 14) | ((n1 & 8) << 21),          \
        (n2 & 1) | ((n2 & 2) << 7) | ((n2 & 4) << 14) | ((n2 & 8) << 21),          \
        (n3 & 1) | ((n3 & 2) << 7) | ((n3 & 4) << 14) | ((n3 & 8) << 21));         \
      *(uint4*)(sA + (buf) * 2048 + s * 1024 + lane * 16) = dv;                    \
    }                                                                              \
    gld16(bsrc0 + ((size_t)(kst) << 10), sBs + (buf) * 2048 + lane * 16);          \
    gld16(bsrc1 + ((size_t)(kst) << 10), sBs + (buf) * 2048 + 1024 + lane * 16);   \
  } while (0)

  STAGE(0, 0);
  __syncthreads();

#pragma unroll 1
  for (int kst = 0; kst < KST; ++kst) {
    const int buf = kst & 1;
    if (kst + 1 < KST) STAGE(buf ^ 1, kst + 1);
    uint4 av0 = *(const uint4*)(sA + buf * 2048 + lane * 16);
    uint4 av1 = *(const uint4*)(sA + buf * 2048 + 1024 + lane * 16);
    uint4 bv0 = *(const uint4*)(sBs + buf * 2048 + lane * 16);
    uint4 bv1 = *(const uint4*)(sBs + buf * 2048 + 1024 + lane * 16);
    i32x4 a0 = __builtin_bit_cast(i32x4, av0), a1 = __builtin_bit_cast(i32x4, av1);
    i32x4 b0 = __builtin_bit_cast(i32x4, bv0), b1 = __builtin_bit_cast(i32x4, bv1);
    acc[0][0] = __builtin_amdgcn_mfma_i32_32x32x32_i8(a0, b0, acc[0][0], 0, 0, 0);
    acc[0][1] = __builtin_amdgcn_mfma_i32_32x32x32_i8(a0, b1, acc[0][1], 0, 0, 0);
    acc[1][0] = __builtin_amdgcn_mfma_i32_32x32x32_i8(a1, b0, acc[1][0], 0, 0, 0);
    acc[1][1] = __builtin_amdgcn_mfma_i32_32x32x32_i8(a1, b1, acc[1][1], 0, 0, 0);
    __syncthreads();
  }
#undef STAGE

  // Epilogue: exact i64 combine of the 5 slices via LDS, f64 output.
  // FULLY UNROLLED (rule #20): every acc index must be compile-time constant,
  // otherwise the whole acc array is demoted to scratch (round-5 regression).
  int* red = (int*)smem;   // [5][64 rows][32 cols]
#pragma unroll
  for (int n = 0; n < 2; ++n) {
    __syncthreads();
#pragma unroll
    for (int m = 0; m < 2; ++m)
#pragma unroll
      for (int r = 0; r < 16; ++r) {
        int row = m * 32 + (r & 3) + ((r >> 2) << 3) + ((lane >> 5) << 2);
        red[(s * 64 + row) * 32 + (lane & 31)] = acc[m][n][r];
      }
    __syncthreads();
    for (int e = tid; e < 2048; e += 320) {
      int row = e >> 5, c = e & 31;
      long long v = 0;
#pragma unroll
      for (int s5 = 0; s5 < 5; ++s5)
        v += (long long)red[(s5 * 64 + row) * 32 + c] * (1LL << (8 * s5));
      int col = col0 + n * 32 + c;
      Cout[(size_t)(row0 + row) * O + col] = (double)v * 0x1p-40 + (double)bias[col];
    }
  }
}

// LIF layer 1: one block per batch row of chunk, 512 threads = H1 neurons.
__global__ __launch_bounds__(512) void lif1(const double* __restrict__ inp1,
                                            uint32_t* __restrict__ spk1, int bBase) {
  int b_local = blockIdx.x;
  int o = threadIdx.x;
  int b = bBase + b_local;
  double mem = 0.0;
  for (int t = 0; t < Tst; ++t) {
    double inp = inp1[((size_t)(b_local * Tst + t)) * H1 + o];
    mem = mem + (inp - mem) / 2.0;
    bool spk = (mem >= 1.0);
    unsigned long long m = __ballot(spk);
    if ((o & 63) == 0) {
      int wv = o >> 6;
      size_t base = ((size_t)(b * Tst + t)) * (H1 / 32);
      spk1[base + wv * 2]     = (uint32_t)(m & 0xffffffffu);
      spk1[base + wv * 2 + 1] = (uint32_t)(m >> 32);
    }
    if (spk) mem = 0.0;
  }
}

// LIF layer 2: one block per batch row of chunk; final membrane out.
__global__ __launch_bounds__(128) void lif2(const double* __restrict__ inp2,
                                            double* __restrict__ mem2, int bBase) {
  int b_local = blockIdx.x;
  int o = threadIdx.x;
  double mem = 0.0;
  for (int t = 0; t < Tst; ++t) {
    double inp = inp2[((size_t)(b_local * Tst + t)) * H2 + o];
    mem = mem + (inp - mem) / 2.0;
    if (mem >= 1.0) mem = 0.0;
  }
  mem2[(size_t)(bBase + b_local) * H2 + o] = mem;
}

// out = mem2 @ Wd^T + bd
__global__ void finalk(const double* __restrict__ mem2, const float* __restrict__ Wd,
                       const float* __restrict__ bd, float* __restrict__ out) {
  int gid = blockIdx.x * blockDim.x + threadIdx.x;
  if (gid >= Bsz * NOUT) return;
  int b = gid / NOUT, j = gid % NOUT;
  double s = (double)bd[j];
  const double* m = mem2 + (size_t)b * H2;
  const float* wr = Wd + (size_t)j * H2;
  for (int k = 0; k < H2; ++k) s = fma(m[k], (double)wr[k], s);
  out[gid] = (float)s;
}

extern "C" void kernel_launch(void* const* d_in, const int* in_sizes, int n_in,
                              void* d_out, int out_size, void* d_ws, size_t ws_size,
                              hipStream_t stream) {
  const float* x  = (const float*)d_in[0];
  const float* W1 = (const float*)d_in[1];
  const float* b1 = (const float*)d_in[2];
  const float* W2 = (const float*)d_in[3];
  const float* b2 = (const float*)d_in[4];
  const float* Wd = (const float*)d_in[5];
  const float* bd = (const float*)d_in[6];
  float* out = (float*)d_out;

  char* ws = (char*)d_ws;
  // Layout (bytes), total ~78 MB:
  double*   inp   = (double*)  (ws);                  // 41,943,040 (chunk inp, reused)
  double*   mem2  = (double*)  (ws + 41943040ull);    //  4,194,304
  uint32_t* sbits = (uint32_t*)(ws + 46137344ull);    // 20,971,520
  uint32_t* spk1  = (uint32_t*)(ws + 67108864ull);    //  5,242,880
  int8_t*   Btl1  = (int8_t*)  (ws + 72351744ull);    //  5,242,880 (5*16*64*1024)
  int8_t*   Btl2  = (int8_t*)  (ws + 77594624ull);    //    327,680 (5*4*16*1024)

  // 1) exact Poisson spike train (bit-packed)
  spikegen<<<dim3(Bsz * Tst * FW / 256), dim3(256), 0, stream>>>(x, sbits);

  // 2) weight digit decomposition (fragment-tiled)
  wslice_i8<<<dim3(512 * 2048 / 256), dim3(256), 0, stream>>>(W1, 512, 2000, 2048, Btl1);
  wslice_i8<<<dim3(128 * 512 / 256),  dim3(256), 0, stream>>>(W2, 128, 512, 512, Btl2);

  // 3) layer 1: 8 chunks of 10240 rows (512 batches)
  for (int c = 0; c < 8; ++c) {
    gemm_i8<2048, 512><<<dim3(160, 8), dim3(320), 0, stream>>>(
        sbits, FW, c * 10240, Btl1, b1, inp);
    lif1<<<dim3(512), dim3(H1), 0, stream>>>(inp, spk1, c * 512);
  }

  // 4) layer 2: 4 chunks of 20480 rows (1024 batches)
  for (int c = 0; c < 4; ++c) {
    gemm_i8<512, 128><<<dim3(320, 2), dim3(320), 0, stream>>>(
        spk1, H1 / 32, c * 20480, Btl2, b2, inp);
    lif2<<<dim3(1024), dim3(H2), 0, stream>>>(inp, mem2, c * 1024);
  }

  // 5) readout
  finalk<<<dim3((Bsz * NOUT + 255) / 256), dim3(256), 0, stream>>>(mem2, Wd, bd, out);
}

// Round 7
// 1422.164 us; speedup vs baseline: 11.9815x; 1.0176x over previous
//
#include <hip/hip_runtime.h>
#include <stdint.h>

typedef int i32x4  __attribute__((ext_vector_type(4)));
typedef int i32x16 __attribute__((ext_vector_type(16)));

constexpr int Bsz  = 4096;
constexpr int Tst  = 20;
constexpr int Fin  = 2000;
constexpr int H1   = 512;
constexpr int H2   = 128;
constexpr int NOUT = 10;
constexpr int FW   = 64;     // words per layer-1 spike row (2048 bits)

// ---------------- Threefry-2x32-20, key = jax.random.key(1) = [0,1] ----------------
__device__ __forceinline__ void tf2x32(uint32_t c0, uint32_t c1, uint32_t& o0, uint32_t& o1) {
  const uint32_t k0 = 0u, k1 = 1u, k2 = 0x1BD11BDBu;
  uint32_t x0 = c0 + k0;
  uint32_t x1 = c1 + k1;
#define ROTL(x,d) (((x)<<(d))|((x)>>(32-(d))))
#define RND(r) { x0 += x1; x1 = ROTL(x1,(r)) ^ x0; }
  RND(13) RND(15) RND(26) RND(6)   x0 += k1; x1 += k2 + 1u;
  RND(17) RND(29) RND(16) RND(24)  x0 += k2; x1 += k0 + 2u;
  RND(13) RND(15) RND(26) RND(6)   x0 += k0; x1 += k1 + 3u;
  RND(17) RND(29) RND(16) RND(24)  x0 += k1; x1 += k2 + 4u;
  RND(13) RND(15) RND(26) RND(6)   x0 += k2; x1 += k0 + 5u;
#undef RND
#undef ROTL
  o0 = x0; o1 = x1;
}

// Partitionable threefry (verified round 2): counter=(0, flat_idx), bits=o0^o1,
// u = bitcast((bits>>9)|0x3f800000)-1 < p.  Integer-equivalent: (bits>>9) < ceil(p*2^23)
// (exact: power-of-2 scale and ceil are exact in f32; lhs is an integer < 2^23).
// Thread = (b, word). Thresholds hoisted once; t-loop inside; 32 evals fully unrolled.
__global__ __launch_bounds__(256) void spikegen2(const float* __restrict__ x,
                                                 uint32_t* __restrict__ sbits) {
  int gid = blockIdx.x * 256 + threadIdx.x;   // 4096*64 threads
  int w = gid & 63;
  int b = gid >> 6;
  int f0 = w * 32;
  const float* xr = x + (size_t)b * Fin;
  uint32_t T[32];
#pragma unroll
  for (int j = 0; j < 32; ++j) {
    int f = f0 + j;
    float p = (f < Fin) ? xr[f] : 0.0f;
    T[j] = (uint32_t)ceilf(p * 8388608.0f);   // ceil(p * 2^23), exact
  }
  uint32_t ibase0 = (uint32_t)(b * Tst) * (uint32_t)Fin + (uint32_t)f0;
#pragma unroll 1
  for (int t = 0; t < Tst; ++t) {
    uint32_t ib = ibase0 + (uint32_t)t * (uint32_t)Fin;
    uint32_t bits = 0;
#pragma unroll
    for (int j = 0; j < 32; ++j) {
      uint32_t o0, o1;
      tf2x32(0u, ib + (uint32_t)j, o0, o1);
      uint32_t v = (o0 ^ o1) >> 9;
      bits |= (v < T[j]) ? (1u << j) : 0u;
    }
    sbits[(size_t)(b * Tst + t) * FW + w] = bits;
  }
}

// Decompose W into 5 balanced base-256 int8 digits on grid 2^-40, written in
// MFMA-fragment-tiled order: Btl[s][nt][kst][ (khalf*32+col)*16 + j ].
__global__ void wslice_i8(const float* __restrict__ W, int O, int K, int KPAD,
                          int8_t* __restrict__ Btl) {
  int idx = blockIdx.x * 256 + threadIdx.x;
  if (idx >= O * KPAD) return;
  int o = idx / KPAD, f = idx % KPAD;
  long long wi = 0;
  if (f < K) wi = llround((double)W[(size_t)o * K + f] * 1099511627776.0);  // 2^40
  int nt = o >> 5, c = o & 31, kst = f >> 5, kh = (f >> 4) & 1, j = f & 15;
  int NT = O >> 5, KST = KPAD >> 5;
  size_t base = (((size_t)nt * KST + kst) << 10) + (size_t)(kh * 32 + c) * 16 + j;
  size_t sstride = ((size_t)NT * KST) << 10;
  long long rem = wi;
#pragma unroll
  for (int s = 0; s < 5; ++s) {
    int d;
    if (s < 4) { d = (int)(int8_t)(rem & 0xff); rem = (rem - d) >> 8; }
    else d = (int)rem;                       // |d| small (|w| <= ~0.12)
    Btl[base + (size_t)s * sstride] = (int8_t)d;
  }
}

// ---------------- i8 MFMA slice GEMM ----------------
typedef const __attribute__((address_space(1))) uint32_t* gas_ptr;
typedef __attribute__((address_space(3))) uint32_t* las_ptr;
__device__ __forceinline__ void gld16(const void* g, void* l) {
  __builtin_amdgcn_global_load_lds((gas_ptr)g, (las_ptr)l, 16, 0, 0);
}

// C[r][col] = (sum_f A_bits[r][f]*W[col][f]) + bias[col], exact via 5 i8 digit slices.
// Block: 320 threads = 5 waves (wave = slice). Tile 64 rows x 64 cols.
// K-unrolled x2: each barrier round stages/consumes 2 K-steps (8 MFMA per wave).
template <int KPAD, int O>
__global__ __launch_bounds__(320) void gemm_i8(
    const uint32_t* __restrict__ Abits, int awords, int rowBase,
    const int8_t* __restrict__ Btl, const float* __restrict__ bias,
    double* __restrict__ Cout) {
  constexpr int KST = KPAD / 32;
  constexpr int NR  = KST / 2;            // barrier rounds
  constexpr int NT  = O / 32;
  __shared__ __align__(16) char smem[49152];
  const int tid = threadIdx.x;
  const int lane = tid & 63;
  const int s = tid >> 6;                 // wave id = slice id
  const int row0 = blockIdx.x * 64;
  const int col0 = blockIdx.y * 64;
  const int nt0 = blockIdx.y * 2;
  const int lrow = lane & 31, lkh = lane >> 5;

  i32x16 acc[2][2] = {};

  // A bit source (waves 0,1 stage m-half = s): 16 bits per lane per K-step.
  const uint8_t* arowp = (const uint8_t*)Abits +
      (size_t)(rowBase + row0 + s * 32 + lrow) * (size_t)(awords * 4) + (size_t)(lkh * 2);
  // B tiled source for this wave's slice (1KB fragment blocks)
  const int8_t* bsrc0 = Btl + ((((size_t)s * NT + nt0) * KST) << 10) + (size_t)lane * 16;
  const int8_t* bsrc1 = Btl + ((((size_t)s * NT + nt0 + 1) * KST) << 10) + (size_t)lane * 16;

  // sA: [2 buf][2 kk][2 m][1024] = 8KB ; sBs(slice): [2 buf][2 kk][2 nt][1024] = 8KB each
  char* sA  = smem;
  char* sBs = smem + 8192 + s * 8192;

#define EXPAND16(bits16) make_uint4(                                            \
      ((bits16) & 1u)        | (((bits16) & 2u)    << 7)  |                     \
      (((bits16) & 4u) << 14)| (((bits16) & 8u)    << 21),                      \
      (((bits16) >> 4) & 1u) | ((((bits16) >> 4) & 2u) << 7) |                  \
      ((((bits16) >> 4) & 4u) << 14) | ((((bits16) >> 4) & 8u) << 21),          \
      (((bits16) >> 8) & 1u) | ((((bits16) >> 8) & 2u) << 7) |                  \
      ((((bits16) >> 8) & 4u) << 14) | ((((bits16) >> 8) & 8u) << 21),          \
      (((bits16) >> 12) & 1u)| ((((bits16) >> 12) & 2u) << 7) |                 \
      ((((bits16) >> 12) & 4u) << 14) | ((((bits16) >> 12) & 8u) << 21))

#define STAGE(buf, r) do {                                                         \
    if (s < 2) {                                                                   \
      uint32_t t0 = *(const unsigned short*)(arowp + (size_t)(2*(r)) * 4);         \
      uint32_t t1 = *(const unsigned short*)(arowp + (size_t)(2*(r)+1) * 4);       \
      *(uint4*)(sA + (buf) * 4096 +        s * 1024 + lane * 16) = EXPAND16(t0);   \
      *(uint4*)(sA + (buf) * 4096 + 2048 + s * 1024 + lane * 16) = EXPAND16(t1);   \
    }                                                                              \
    gld16(bsrc0 + ((size_t)(2*(r))   << 10), sBs + (buf) * 4096 +        lane * 16);       \
    gld16(bsrc0 + ((size_t)(2*(r)+1) << 10), sBs + (buf) * 4096 + 2048 + lane * 16);       \
    gld16(bsrc1 + ((size_t)(2*(r))   << 10), sBs + (buf) * 4096 + 1024 + lane * 16);       \
    gld16(bsrc1 + ((size_t)(2*(r)+1) << 10), sBs + (buf) * 4096 + 2048 + 1024 + lane * 16);\
  } while (0)

  STAGE(0, 0);
  __syncthreads();

#pragma unroll 1
  for (int r = 0; r < NR; ++r) {
    const int buf = r & 1;
    if (r + 1 < NR) STAGE(buf ^ 1, r + 1);
#pragma unroll
    for (int kk = 0; kk < 2; ++kk) {
      uint4 av0 = *(const uint4*)(sA + buf * 4096 + kk * 2048 +        lane * 16);
      uint4 av1 = *(const uint4*)(sA + buf * 4096 + kk * 2048 + 1024 + lane * 16);
      uint4 bv0 = *(const uint4*)(sBs + buf * 4096 + kk * 2048 +        lane * 16);
      uint4 bv1 = *(const uint4*)(sBs + buf * 4096 + kk * 2048 + 1024 + lane * 16);
      i32x4 a0 = __builtin_bit_cast(i32x4, av0), a1 = __builtin_bit_cast(i32x4, av1);
      i32x4 b0 = __builtin_bit_cast(i32x4, bv0), b1 = __builtin_bit_cast(i32x4, bv1);
      acc[0][0] = __builtin_amdgcn_mfma_i32_32x32x32_i8(a0, b0, acc[0][0], 0, 0, 0);
      acc[0][1] = __builtin_amdgcn_mfma_i32_32x32x32_i8(a0, b1, acc[0][1], 0, 0, 0);
      acc[1][0] = __builtin_amdgcn_mfma_i32_32x32x32_i8(a1, b0, acc[1][0], 0, 0, 0);
      acc[1][1] = __builtin_amdgcn_mfma_i32_32x32x32_i8(a1, b1, acc[1][1], 0, 0, 0);
    }
    __syncthreads();
  }
#undef STAGE
#undef EXPAND16

  // Epilogue: exact i64 combine of the 5 slices via LDS, f64 output.
  // FULLY UNROLLED (rule #20): every acc index compile-time constant.
  int* red = (int*)smem;   // [5][64 rows][32 cols]
#pragma unroll
  for (int n = 0; n < 2; ++n) {
    __syncthreads();
#pragma unroll
    for (int m = 0; m < 2; ++m)
#pragma unroll
      for (int r = 0; r < 16; ++r) {
        int row = m * 32 + (r & 3) + ((r >> 2) << 3) + ((lane >> 5) << 2);
        red[(s * 64 + row) * 32 + (lane & 31)] = acc[m][n][r];
      }
    __syncthreads();
    for (int e = tid; e < 2048; e += 320) {
      int row = e >> 5, c = e & 31;
      long long v = 0;
#pragma unroll
      for (int s5 = 0; s5 < 5; ++s5)
        v += (long long)red[(s5 * 64 + row) * 32 + c] * (1LL << (8 * s5));
      int col = col0 + n * 32 + c;
      Cout[(size_t)(row0 + row) * O + col] = (double)v * 0x1p-40 + (double)bias[col];
    }
  }
}

// LIF layer 1: one block per batch row of chunk, 512 threads = H1 neurons.
__global__ __launch_bounds__(512) void lif1(const double* __restrict__ inp1,
                                            uint32_t* __restrict__ spk1, int bBase) {
  int b_local = blockIdx.x;
  int o = threadIdx.x;
  int b = bBase + b_local;
  double mem = 0.0;
  for (int t = 0; t < Tst; ++t) {
    double inp = inp1[((size_t)(b_local * Tst + t)) * H1 + o];
    mem = mem + (inp - mem) / 2.0;
    bool spk = (mem >= 1.0);
    unsigned long long m = __ballot(spk);
    if ((o & 63) == 0) {
      int wv = o >> 6;
      size_t base = ((size_t)(b * Tst + t)) * (H1 / 32);
      spk1[base + wv * 2]     = (uint32_t)(m & 0xffffffffu);
      spk1[base + wv * 2 + 1] = (uint32_t)(m >> 32);
    }
    if (spk) mem = 0.0;
  }
}

// LIF layer 2: one block per batch row of chunk; final membrane out.
__global__ __launch_bounds__(128) void lif2(const double* __restrict__ inp2,
                                            double* __restrict__ mem2, int bBase) {
  int b_local = blockIdx.x;
  int o = threadIdx.x;
  double mem = 0.0;
  for (int t = 0; t < Tst; ++t) {
    double inp = inp2[((size_t)(b_local * Tst + t)) * H2 + o];
    mem = mem + (inp - mem) / 2.0;
    if (mem >= 1.0) mem = 0.0;
  }
  mem2[(size_t)(bBase + b_local) * H2 + o] = mem;
}

// out = mem2 @ Wd^T + bd
__global__ void finalk(const double* __restrict__ mem2, const float* __restrict__ Wd,
                       const float* __restrict__ bd, float* __restrict__ out) {
  int gid = blockIdx.x * blockDim.x + threadIdx.x;
  if (gid >= Bsz * NOUT) return;
  int b = gid / NOUT, j = gid % NOUT;
  double s = (double)bd[j];
  const double* m = mem2 + (size_t)b * H2;
  const float* wr = Wd + (size_t)j * H2;
  for (int k = 0; k < H2; ++k) s = fma(m[k], (double)wr[k], s);
  out[gid] = (float)s;
}

extern "C" void kernel_launch(void* const* d_in, const int* in_sizes, int n_in,
                              void* d_out, int out_size, void* d_ws, size_t ws_size,
                              hipStream_t stream) {
  const float* x  = (const float*)d_in[0];
  const float* W1 = (const float*)d_in[1];
  const float* b1 = (const float*)d_in[2];
  const float* W2 = (const float*)d_in[3];
  const float* b2 = (const float*)d_in[4];
  const float* Wd = (const float*)d_in[5];
  const float* bd = (const float*)d_in[6];
  float* out = (float*)d_out;

  char* ws = (char*)d_ws;
  // Layout (bytes), total ~78 MB:
  double*   inp   = (double*)  (ws);                  // 41,943,040 (chunk inp, reused)
  double*   mem2  = (double*)  (ws + 41943040ull);    //  4,194,304
  uint32_t* sbits = (uint32_t*)(ws + 46137344ull);    // 20,971,520
  uint32_t* spk1  = (uint32_t*)(ws + 67108864ull);    //  5,242,880
  int8_t*   Btl1  = (int8_t*)  (ws + 72351744ull);    //  5,242,880 (5*16*64*1024)
  int8_t*   Btl2  = (int8_t*)  (ws + 77594624ull);    //    327,680 (5*4*16*1024)

  // 1) exact Poisson spike train (bit-packed)
  spikegen2<<<dim3(Bsz * 64 / 256), dim3(256), 0, stream>>>(x, sbits);

  // 2) weight digit decomposition (fragment-tiled)
  wslice_i8<<<dim3(512 * 2048 / 256), dim3(256), 0, stream>>>(W1, 512, 2000, 2048, Btl1);
  wslice_i8<<<dim3(128 * 512 / 256),  dim3(256), 0, stream>>>(W2, 128, 512, 512, Btl2);

  // 3) layer 1: 8 chunks of 10240 rows (512 batches)
  for (int c = 0; c < 8; ++c) {
    gemm_i8<2048, 512><<<dim3(160, 8), dim3(320), 0, stream>>>(
        sbits, FW, c * 10240, Btl1, b1, inp);
    lif1<<<dim3(512), dim3(H1), 0, stream>>>(inp, spk1, c * 512);
  }

  // 4) layer 2: 4 chunks of 20480 rows (1024 batches)
  for (int c = 0; c < 4; ++c) {
    gemm_i8<512, 128><<<dim3(320, 2), dim3(320), 0, stream>>>(
        spk1, H1 / 32, c * 20480, Btl2, b2, inp);
    lif2<<<dim3(1024), dim3(H2), 0, stream>>>(inp, mem2, c * 1024);
  }

  // 5) readout
  finalk<<<dim3((Bsz * NOUT + 255) / 256), dim3(256), 0, stream>>>(mem2, Wd, bd, out);
}